// Round 2
// baseline (121.088 us; speedup 1.0000x reference)
//
#include <hip/hip_runtime.h>
#include <stdint.h>

// BinaryTreeLogicNet: out = sigmoid(tree_gcd(sigmoid(x @ W^T - 2)) * w_out + b_out)
// M=65536 rows, L=256 leaves.
// R9: single-kernel rev. Evidence from R8 profile: btln_main < 41 us (absent
// from fill-dominated top-5); dur_us is ~80 us harness fills + ~35 us ours.
//   - convert_w ELIMINATED (was a serialized dependent launch ~5-10 us):
//     each block stages W K-tiles straight from fp32 W_leaf (L2-resident,
//     512x256KB = 128MB cache reads) via reg->f2bf->ds_write_b64, writing
//     the BYTE-IDENTICAL swizzled layout of the old img (nibble-swap row
//     permute + cpos^(j&7) XOR) so the verified MFMA read path is untouched.
//   - pv param table built per-block in prologue.
//   - x prefetch back to R7-style rolling one-tile-ahead (R8's upfront
//     preload serialized HBM delivery: 118.1 vs 113.7).
//   - Tree epilogue identical (verified: absmax 0.00390625).

#define EPS 1e-6f
#define LOG2E 1.44269504088896340736f

typedef __attribute__((ext_vector_type(8))) short short8;
typedef __attribute__((ext_vector_type(4))) short short4_t;
typedef __attribute__((ext_vector_type(4))) float float4_t;

__device__ __forceinline__ float fast_sigmoid(float z) {
    float e = __builtin_amdgcn_exp2f(-z * LOG2E);
    return __builtin_amdgcn_rcpf(1.0f + e);
}

__device__ __forceinline__ short f2bf(float f) {   // fp32 -> bf16 RNE
    uint32_t u = __builtin_bit_cast(uint32_t, f);
    u += 0x7FFFu + ((u >> 16) & 1u);
    return (short)(u >> 16);
}

__device__ __forceinline__ short8 pack8(float4 a, float4 b) {
    short8 s;
    s[0] = f2bf(a.x); s[1] = f2bf(a.y); s[2] = f2bf(a.z); s[3] = f2bf(a.w);
    s[4] = f2bf(b.x); s[5] = f2bf(b.y); s[6] = f2bf(b.z); s[7] = f2bf(b.w);
    return s;
}

__device__ __forceinline__ float ggcd(float l, float r, float lam) {
    float a = fabsf(l) + EPS;
    float b = fabsf(r) + EPS;
    float mn = fminf(a, b);
    float mx = fmaxf(a, b);
    return fmaf(lam, mn - mx, mx);   // lam*mn + (1-lam)*mx
}

// Stage one 32 KB W K-tile (kt) into dst, byte-identical to the old img:
//   LDS byte j*128 + cpos*16 + h*8 holds
//   bf16x4( W[swap(j)][kt*64 + ((cpos^(j&7))<<3) + h*4 .. +4) )
// Thread t covers 8 slots: j = i*32 + (t>>4), (cpos,h) from (m+4g)&15
// (bank-spread: 4-way b64 conflicts = 1.58x, acceptable).
__device__ __forceinline__ void stage_tile(const float* __restrict__ Wl,
                                           short* dst, int kt, int tid) {
    const int m  = tid & 15;
    const int g  = (tid >> 4) & 3;
    const int jb = tid >> 4;                     // 0..31
    const int cpos2h = (m + 4 * g) & 15;
    const int cpos = cpos2h >> 1;
    const int h    = cpos2h & 1;
    #pragma unroll
    for (int i = 0; i < 8; ++i) {
        int j   = i * 32 + jb;
        int col = kt * 64 + ((cpos ^ (j & 7)) << 3) + h * 4;
        int src = ((j & 15) << 4) | (j >> 4);    // nibble-swap (involution)
        float4 w4 = *(const float4*)&Wl[src * 256 + col];
        short4_t s4;
        s4.x = f2bf(w4.x); s4.y = f2bf(w4.y); s4.z = f2bf(w4.z); s4.w = f2bf(w4.w);
        *(short4_t*)((char*)dst + j * 128 + cpos2h * 8) = s4;
    }
}

// tree levels 1-4 on one 16-acc row-group; acc consumed in place
__device__ __forceinline__ void tree_reduce(float4_t acc[16], int c0,
                                            const float4* pv, float res[4]) {
    #pragma unroll
    for (int t = 0; t < 16; ++t) {
        #pragma unroll
        for (int r = 0; r < 4; ++r) acc[t][r] = fast_sigmoid(acc[t][r] - 2.0f);
    }
    #pragma unroll
    for (int tp = 0; tp < 8; ++tp) {          // level 1 (off 0)
        float4 p = pv[c0 * 8 + tp];
        #pragma unroll
        for (int r = 0; r < 4; ++r)
            acc[tp][r] = ggcd(acc[2*tp][r] * p.x, acc[2*tp+1][r] * p.y, p.z);
    }
    #pragma unroll
    for (int tp = 0; tp < 4; ++tp) {          // level 2 (off 128)
        float4 p = pv[128 + c0 * 4 + tp];
        #pragma unroll
        for (int r = 0; r < 4; ++r)
            acc[tp][r] = ggcd(acc[2*tp][r] * p.x, acc[2*tp+1][r] * p.y, p.z);
    }
    #pragma unroll
    for (int tp = 0; tp < 2; ++tp) {          // level 3 (off 192)
        float4 p = pv[192 + c0 * 2 + tp];
        #pragma unroll
        for (int r = 0; r < 4; ++r)
            acc[tp][r] = ggcd(acc[2*tp][r] * p.x, acc[2*tp+1][r] * p.y, p.z);
    }
    {                                          // level 4 (off 224)
        float4 p = pv[224 + c0];
        #pragma unroll
        for (int r = 0; r < 4; ++r)
            res[r] = ggcd(acc[0][r] * p.x, acc[1][r] * p.y, p.z);
    }
}

// ---- main (and only) kernel ----
__global__ __launch_bounds__(512, 4)
void btln_main(const float* __restrict__ x, const float* __restrict__ Wl,
               const float* __restrict__ wts, const float* __restrict__ bia,
               const float* __restrict__ wout, const float* __restrict__ bout,
               float* __restrict__ out) {
    __shared__ short Wt[2][16384];           // 2 x 32 KB W K-tiles
    __shared__ float4 pv[256];               // 4 KB packed (w0,w1,lam)

    const int tid  = threadIdx.x;
    const int lane = tid & 63;
    const int wv   = tid >> 6;               // wave 0..7
    const int c0   = lane & 15;
    const int q    = lane >> 4;

    // pv build (255 real entries + zero pad)
    if (tid < 255) {
        pv[tid] = make_float4(wts[2 * tid], wts[2 * tid + 1],
                              fast_sigmoid(bia[tid]), 0.f);
    } else if (tid == 255) {
        pv[255] = make_float4(0.f, 0.f, 0.f, 0.f);
    }

    // stage tile 0
    stage_tile(Wl, Wt[0], 0, tid);

    const int rowbase = blockIdx.x * 128 + wv * 16;
    const float* xr = x + (size_t)(rowbase + c0) * 256;

    // A-frags for tile 0 (lane(c0,q) <- row c0, k q*8.. / 32+q*8..)
    float4 r0 = *(const float4*)(xr + q * 8);
    float4 r1 = *(const float4*)(xr + q * 8 + 4);
    float4 r2 = *(const float4*)(xr + 32 + q * 8);
    float4 r3 = *(const float4*)(xr + 32 + q * 8 + 4);
    short8 afc0 = pack8(r0, r1);
    short8 afc1 = pack8(r2, r3);

    float4_t acc[16];
    #pragma unroll
    for (int t = 0; t < 16; ++t) acc[t] = (float4_t){0.f, 0.f, 0.f, 0.f};

    __syncthreads();                          // tile 0 + pv resident

    const int vx = c0 & 7;

    // ---- K loop, fully unrolled; rolling x prefetch one tile ahead ----
#define KSTEP(kt, LAST)                                                       \
    {                                                                         \
        const short* cur = Wt[(kt) & 1];                                      \
        float4 n0, n1, n2, n3;                                                \
        if (!(LAST)) {                        /* issue next x chunk early */  \
            const float* xn = xr + ((kt) + 1) * 64;                           \
            n0 = *(const float4*)(xn + q * 8);                                \
            n1 = *(const float4*)(xn + q * 8 + 4);                            \
            n2 = *(const float4*)(xn + 32 + q * 8);                           \
            n3 = *(const float4*)(xn + 32 + q * 8 + 4);                       \
        }                                                                     \
        _Pragma("unroll")                                                     \
        for (int t = 0; t < 16; ++t) {                                        \
            const short* base = &cur[(t * 16 + c0) * 64];                     \
            short8 bf0 = *(const short8*)&base[(q ^ vx) * 8];                 \
            short8 bf1 = *(const short8*)&base[((q + 4) ^ vx) * 8];           \
            acc[t] = __builtin_amdgcn_mfma_f32_16x16x32_bf16(                 \
                afc0, bf0, acc[t], 0, 0, 0);                                  \
            acc[t] = __builtin_amdgcn_mfma_f32_16x16x32_bf16(                 \
                afc1, bf1, acc[t], 0, 0, 0);                                  \
        }                                                                     \
        __builtin_amdgcn_sched_barrier(0);    /* keep stage loads below */    \
        if (!(LAST)) {                                                        \
            stage_tile(Wl, Wt[((kt) + 1) & 1], (kt) + 1, tid);                \
            afc0 = pack8(n0, n1);                                             \
            afc1 = pack8(n2, n3);                                             \
            __syncthreads();                  /* writes + packs done */       \
        }                                                                     \
    }

    KSTEP(0, 0)
    KSTEP(1, 0)
    KSTEP(2, 0)
    KSTEP(3, 1)
#undef KSTEP

    // ---- epilogue: leaf sigmoid + tree (acc[t][r]: row q*4+r, leaf c0*16+t) ----
    float res[4];
    tree_reduce(acc, c0, pv, res);

    const int offs[4] = {240, 248, 252, 254};
    #pragma unroll
    for (int k = 0; k < 4; ++k) {             // levels 5-8: butterfly across c0
        float4 p = pv[offs[k] + (c0 >> (k + 1))];
        bool isLeft = ((c0 >> k) & 1) == 0;
        #pragma unroll
        for (int r = 0; r < 4; ++r) {
            float other = __shfl_xor(res[r], 1 << k, 64);
            float lf = isLeft ? res[r] : other;
            float rt = isLeft ? other  : res[r];
            res[r] = ggcd(lf * p.x, rt * p.y, p.z);
        }
    }

    if (c0 == 0) {
        const float wo = wout[0];
        const float bo = bout[0];
        #pragma unroll
        for (int r = 0; r < 4; ++r)
            out[rowbase + q * 4 + r] = fast_sigmoid(fmaf(res[r], wo, bo));
    }
}

extern "C" void kernel_launch(void* const* d_in, const int* in_sizes, int n_in,
                              void* d_out, int out_size, void* d_ws, size_t ws_size,
                              hipStream_t stream) {
    const float* x   = (const float*)d_in[0];
    const float* Wl  = (const float*)d_in[1];
    const float* wts = (const float*)d_in[2];
    const float* bia = (const float*)d_in[3];
    const float* wo  = (const float*)d_in[4];
    const float* bo  = (const float*)d_in[5];
    float* out = (float*)d_out;

    const int rows = out_size;                // 65536
    dim3 grid(rows / 128), block(512);        // 512 blocks x 8 waves, 2 blocks/CU
    btln_main<<<grid, block, 0, stream>>>(x, Wl, wts, bia, wo, bo, out);
}

// Round 3
// 116.331 us; speedup vs baseline: 1.0409x; 1.0409x over previous
//
#include <hip/hip_runtime.h>
#include <stdint.h>

// BinaryTreeLogicNet: out = sigmoid(tree_gcd(sigmoid(x @ W^T - 2)) * w_out + b_out)
// M=65536 rows, L=256 leaves.
// R10: fix the R9 schedule (50us kernel, MfmaUtil 6%, nothing saturated ->
// stall-bound). R9 pinned staging AFTER the MFMA phase then barrier'd -> L2
// latency fully exposed per kt (T14 backwards). Changes:
//   - T14 split: next-tile W global loads + next x loads issued at TOP of
//     each K-step; convert+ds_write after the MFMA halves (double-buffered
//     LDS so writes land while current buffer is read). 1 barrier/kt.
//   - 4-sub-phase interleave caps live regs (~58 VGPR + 64 AGPR < 128).
//   - Write-side bank fix (measured 2.29M conflict cycles = even-banks-only
//     ds_write_b64): each lane now owns one full 16B slot (short8 store),
//     banks cpos*4+0..3 -> all 32 banks, 2-way max (free).
//   - LDS tile byte layout IDENTICAL to R7/R9 (nibble-swap row permute +
//     cpos^(j&7) XOR) -> verified MFMA read path + tree epilogue untouched
//     (absmax 0.00390625).

#define EPS 1e-6f
#define LOG2E 1.44269504088896340736f

typedef __attribute__((ext_vector_type(8))) short short8;
typedef __attribute__((ext_vector_type(4))) short short4_t;
typedef __attribute__((ext_vector_type(4))) float float4_t;

__device__ __forceinline__ float fast_sigmoid(float z) {
    float e = __builtin_amdgcn_exp2f(-z * LOG2E);
    return __builtin_amdgcn_rcpf(1.0f + e);
}

__device__ __forceinline__ short f2bf(float f) {   // fp32 -> bf16 RNE
    uint32_t u = __builtin_bit_cast(uint32_t, f);
    u += 0x7FFFu + ((u >> 16) & 1u);
    return (short)(u >> 16);
}

__device__ __forceinline__ short8 pack8(float4 a, float4 b) {
    short8 s;
    s[0] = f2bf(a.x); s[1] = f2bf(a.y); s[2] = f2bf(a.z); s[3] = f2bf(a.w);
    s[4] = f2bf(b.x); s[5] = f2bf(b.y); s[6] = f2bf(b.z); s[7] = f2bf(b.w);
    return s;
}

__device__ __forceinline__ float ggcd(float l, float r, float lam) {
    float a = fabsf(l) + EPS;
    float b = fabsf(r) + EPS;
    float mn = fminf(a, b);
    float mx = fmaxf(a, b);
    return fmaf(lam, mn - mx, mx);   // lam*mn + (1-lam)*mx
}

// tree levels 1-4 on one 16-acc row-group; acc consumed in place
__device__ __forceinline__ void tree_reduce(float4_t acc[16], int c0,
                                            const float4* pv, float res[4]) {
    #pragma unroll
    for (int t = 0; t < 16; ++t) {
        #pragma unroll
        for (int r = 0; r < 4; ++r) acc[t][r] = fast_sigmoid(acc[t][r] - 2.0f);
    }
    #pragma unroll
    for (int tp = 0; tp < 8; ++tp) {          // level 1 (off 0)
        float4 p = pv[c0 * 8 + tp];
        #pragma unroll
        for (int r = 0; r < 4; ++r)
            acc[tp][r] = ggcd(acc[2*tp][r] * p.x, acc[2*tp+1][r] * p.y, p.z);
    }
    #pragma unroll
    for (int tp = 0; tp < 4; ++tp) {          // level 2 (off 128)
        float4 p = pv[128 + c0 * 4 + tp];
        #pragma unroll
        for (int r = 0; r < 4; ++r)
            acc[tp][r] = ggcd(acc[2*tp][r] * p.x, acc[2*tp+1][r] * p.y, p.z);
    }
    #pragma unroll
    for (int tp = 0; tp < 2; ++tp) {          // level 3 (off 192)
        float4 p = pv[192 + c0 * 2 + tp];
        #pragma unroll
        for (int r = 0; r < 4; ++r)
            acc[tp][r] = ggcd(acc[2*tp][r] * p.x, acc[2*tp+1][r] * p.y, p.z);
    }
    {                                          // level 4 (off 224)
        float4 p = pv[224 + c0];
        #pragma unroll
        for (int r = 0; r < 4; ++r)
            res[r] = ggcd(acc[0][r] * p.x, acc[1][r] * p.y, p.z);
    }
}

// ---- main (and only) kernel ----
__global__ __launch_bounds__(512, 4)
void btln_main(const float* __restrict__ x, const float* __restrict__ Wl,
               const float* __restrict__ wts, const float* __restrict__ bia,
               const float* __restrict__ wout, const float* __restrict__ bout,
               float* __restrict__ out) {
    __shared__ short Wt[2][16384];           // 2 x 32 KB W K-tiles
    __shared__ float4 pv[256];               // 4 KB packed (w0,w1,lam)

    const int tid  = threadIdx.x;
    const int lane = tid & 63;
    const int wv   = tid >> 6;               // wave 0..7
    const int c0   = lane & 15;
    const int q    = lane >> 4;

    // ---- staging coords: thread owns one 16B slot (row j, chunk cpos) per pass
    // LDS byte p*8192 + sjj*128 + scpos*16 holds bf16x8 of
    //   W[swap(j)][kt*64 + ((scpos^(j&7))<<3) .. +8),  j = p*64+sjj
    const int scpos = tid & 7;
    const int sjj   = tid >> 3;                       // 0..63
    const int scol  = (scpos ^ (sjj & 7)) << 3;       // j&7 == sjj&7
    const int j0 = sjj,       j1 = 64 + sjj,  j2 = 128 + sjj, j3 = 192 + sjj;
    const int ssrc0 = ((j0 & 15) << 4) | (j0 >> 4);   // nibble-swap (involution)
    const int ssrc1 = ((j1 & 15) << 4) | (j1 >> 4);
    const int ssrc2 = ((j2 & 15) << 4) | (j2 >> 4);
    const int ssrc3 = ((j3 & 15) << 4) | (j3 >> 4);
    const int wslot = sjj * 128 + scpos * 16;         // byte off within tile

    // pv build (255 real entries + zero pad)
    if (tid < 255) {
        pv[tid] = make_float4(wts[2 * tid], wts[2 * tid + 1],
                              fast_sigmoid(bia[tid]), 0.f);
    } else if (tid == 255) {
        pv[255] = make_float4(0.f, 0.f, 0.f, 0.f);
    }

    // ---- prologue: stage tile 0 (cold, latency exposed once) ----
    {
        const float* wsrc = Wl + scol;                // kt = 0
        char* wb = (char*)&Wt[0][0] + wslot;
        float4 a0 = *(const float4*)(wsrc + ssrc0 * 256);
        float4 b0 = *(const float4*)(wsrc + ssrc0 * 256 + 4);
        float4 a1 = *(const float4*)(wsrc + ssrc1 * 256);
        float4 b1 = *(const float4*)(wsrc + ssrc1 * 256 + 4);
        float4 a2 = *(const float4*)(wsrc + ssrc2 * 256);
        float4 b2 = *(const float4*)(wsrc + ssrc2 * 256 + 4);
        float4 a3 = *(const float4*)(wsrc + ssrc3 * 256);
        float4 b3 = *(const float4*)(wsrc + ssrc3 * 256 + 4);
        *(short8*)(wb)         = pack8(a0, b0);
        *(short8*)(wb + 8192)  = pack8(a1, b1);
        *(short8*)(wb + 16384) = pack8(a2, b2);
        *(short8*)(wb + 24576) = pack8(a3, b3);
    }

    const int rowbase = blockIdx.x * 128 + wv * 16;
    const float* xr = x + (size_t)(rowbase + c0) * 256;

    // A-frags for tile 0
    float4 r0 = *(const float4*)(xr + q * 8);
    float4 r1 = *(const float4*)(xr + q * 8 + 4);
    float4 r2 = *(const float4*)(xr + 32 + q * 8);
    float4 r3 = *(const float4*)(xr + 32 + q * 8 + 4);
    short8 afc0 = pack8(r0, r1);
    short8 afc1 = pack8(r2, r3);

    float4_t acc[16];
    #pragma unroll
    for (int t = 0; t < 16; ++t) acc[t] = (float4_t){0.f, 0.f, 0.f, 0.f};

    __syncthreads();                          // tile 0 + pv resident

    const int vx = c0 & 7;

    // ---- K loop, fully unrolled; T14 async-STAGE split, 4 sub-phases ----
#define MFMA_T(t)                                                             \
    {                                                                         \
        const short* base = &cur[((t) * 16 + c0) * 64];                       \
        short8 bf0 = *(const short8*)&base[(q ^ vx) * 8];                     \
        short8 bf1 = *(const short8*)&base[((q + 4) ^ vx) * 8];               \
        acc[t] = __builtin_amdgcn_mfma_f32_16x16x32_bf16(                     \
            afc0, bf0, acc[t], 0, 0, 0);                                      \
        acc[t] = __builtin_amdgcn_mfma_f32_16x16x32_bf16(                     \
            afc1, bf1, acc[t], 0, 0, 0);                                      \
    }

#define KSTEP(kt, LAST)                                                       \
    {                                                                         \
        const short* cur = Wt[(kt) & 1];                                      \
        char* wbn = (char*)&Wt[((kt) + 1) & 1][0] + wslot;                    \
        const float* wsrc = Wl + ((kt) + 1) * 64 + scol;                      \
        float4 s0, s1, s2, s3, n0, n1, n2, n3;                                \
        if (!(LAST)) {                        /* issue-early: stage half 1 */ \
            s0 = *(const float4*)(wsrc + ssrc0 * 256);                        \
            s1 = *(const float4*)(wsrc + ssrc0 * 256 + 4);                    \
            s2 = *(const float4*)(wsrc + ssrc1 * 256);                        \
            s3 = *(const float4*)(wsrc + ssrc1 * 256 + 4);                    \
            const float* xn = xr + ((kt) + 1) * 64;   /* next x frags */      \
            n0 = *(const float4*)(xn + q * 8);                                \
            n1 = *(const float4*)(xn + q * 8 + 4);                            \
            n2 = *(const float4*)(xn + 32 + q * 8);                           \
            n3 = *(const float4*)(xn + 32 + q * 8 + 4);                       \
            __builtin_amdgcn_sched_barrier(0);                                \
        }                                                                     \
        _Pragma("unroll")                                                     \
        for (int t = 0; t < 8; ++t) MFMA_T(t)                                 \
        __builtin_amdgcn_sched_barrier(0);                                    \
        float4 u0, u1, u2, u3;                                                \
        if (!(LAST)) {                        /* write half 1, load half 2 */ \
            *(short8*)(wbn)        = pack8(s0, s1);                           \
            *(short8*)(wbn + 8192) = pack8(s2, s3);                           \
            u0 = *(const float4*)(wsrc + ssrc2 * 256);                        \
            u1 = *(const float4*)(wsrc + ssrc2 * 256 + 4);                    \
            u2 = *(const float4*)(wsrc + ssrc3 * 256);                        \
            u3 = *(const float4*)(wsrc + ssrc3 * 256 + 4);                    \
            __builtin_amdgcn_sched_barrier(0);                                \
        }                                                                     \
        _Pragma("unroll")                                                     \
        for (int t = 8; t < 16; ++t) MFMA_T(t)                                \
        __builtin_amdgcn_sched_barrier(0);                                    \
        if (!(LAST)) {                        /* write half 2, pack x */      \
            *(short8*)(wbn + 16384) = pack8(u0, u1);                          \
            *(short8*)(wbn + 24576) = pack8(u2, u3);                          \
            afc0 = pack8(n0, n1);                                             \
            afc1 = pack8(n2, n3);                                             \
            __syncthreads();                  /* writes drained, tile ready */\
        }                                                                     \
    }

    KSTEP(0, 0)
    KSTEP(1, 0)
    KSTEP(2, 0)
    KSTEP(3, 1)
#undef KSTEP
#undef MFMA_T

    // ---- epilogue: leaf sigmoid + tree (acc[t][r]: row q*4+r, leaf c0*16+t) ----
    float res[4];
    tree_reduce(acc, c0, pv, res);

    const int offs[4] = {240, 248, 252, 254};
    #pragma unroll
    for (int k = 0; k < 4; ++k) {             // levels 5-8: butterfly across c0
        float4 p = pv[offs[k] + (c0 >> (k + 1))];
        bool isLeft = ((c0 >> k) & 1) == 0;
        #pragma unroll
        for (int r = 0; r < 4; ++r) {
            float other = __shfl_xor(res[r], 1 << k, 64);
            float lf = isLeft ? res[r] : other;
            float rt = isLeft ? other  : res[r];
            res[r] = ggcd(lf * p.x, rt * p.y, p.z);
        }
    }

    if (c0 == 0) {
        const float wo = wout[0];
        const float bo = bout[0];
        #pragma unroll
        for (int r = 0; r < 4; ++r)
            out[rowbase + q * 4 + r] = fast_sigmoid(fmaf(res[r], wo, bo));
    }
}

extern "C" void kernel_launch(void* const* d_in, const int* in_sizes, int n_in,
                              void* d_out, int out_size, void* d_ws, size_t ws_size,
                              hipStream_t stream) {
    const float* x   = (const float*)d_in[0];
    const float* Wl  = (const float*)d_in[1];
    const float* wts = (const float*)d_in[2];
    const float* bia = (const float*)d_in[3];
    const float* wo  = (const float*)d_in[4];
    const float* bo  = (const float*)d_in[5];
    float* out = (float*)d_out;

    const int rows = out_size;                // 65536
    dim3 grid(rows / 128), block(512);        // 512 blocks x 8 waves, 2 blocks/CU
    btln_main<<<grid, block, 0, stream>>>(x, Wl, wts, bia, wo, bo, out);
}

// Round 4
// 114.627 us; speedup vs baseline: 1.0564x; 1.0149x over previous
//
#include <hip/hip_runtime.h>
#include <stdint.h>

// BinaryTreeLogicNet: out = sigmoid(tree_gcd(sigmoid(x @ W^T - 2)) * w_out + b_out)
// M=65536 rows, L=256 leaves.
// R11: barrier-free steady state. R9 counters said stall-bound (MfmaUtil 6%,
// nothing saturated); R10 still barrier'd 8 waves every K-tile and staged W
// per-block (2x per CU). Changes:
//   - ONE 1024-thread block per CU (grid=256, 16 waves). LDS holds ALL FOUR
//     W K-tiles single-buffered (128 KB + 4 KB pv <= 160 KB).
//   - W staged ONCE in prologue (same byte-identical swizzled tile layout:
//     nibble-swap row permute + cpos^(j&7) XOR), one __syncthreads, then a
//     fully-unrolled K loop with NO barriers: per kt {issue next x frags,
//     32 ds_read_b128 + 32 MFMA, pack}. Waves free-run; epilogue decoupled.
//   - W staging traffic per CU halved (staged once, not per 2 blocks).
//   - MFMA read path + tree epilogue untouched (verified absmax 0.00390625).

#define EPS 1e-6f
#define LOG2E 1.44269504088896340736f

typedef __attribute__((ext_vector_type(8))) short short8;
typedef __attribute__((ext_vector_type(4))) short short4_t;
typedef __attribute__((ext_vector_type(4))) float float4_t;

__device__ __forceinline__ float fast_sigmoid(float z) {
    float e = __builtin_amdgcn_exp2f(-z * LOG2E);
    return __builtin_amdgcn_rcpf(1.0f + e);
}

__device__ __forceinline__ short f2bf(float f) {   // fp32 -> bf16 RNE
    uint32_t u = __builtin_bit_cast(uint32_t, f);
    u += 0x7FFFu + ((u >> 16) & 1u);
    return (short)(u >> 16);
}

__device__ __forceinline__ short8 pack8(float4 a, float4 b) {
    short8 s;
    s[0] = f2bf(a.x); s[1] = f2bf(a.y); s[2] = f2bf(a.z); s[3] = f2bf(a.w);
    s[4] = f2bf(b.x); s[5] = f2bf(b.y); s[6] = f2bf(b.z); s[7] = f2bf(b.w);
    return s;
}

__device__ __forceinline__ float ggcd(float l, float r, float lam) {
    float a = fabsf(l) + EPS;
    float b = fabsf(r) + EPS;
    float mn = fminf(a, b);
    float mx = fmaxf(a, b);
    return fmaf(lam, mn - mx, mx);   // lam*mn + (1-lam)*mx
}

// tree levels 1-4 on one 16-acc row-group; acc consumed in place
__device__ __forceinline__ void tree_reduce(float4_t acc[16], int c0,
                                            const float4* pv, float res[4]) {
    #pragma unroll
    for (int t = 0; t < 16; ++t) {
        #pragma unroll
        for (int r = 0; r < 4; ++r) acc[t][r] = fast_sigmoid(acc[t][r] - 2.0f);
    }
    #pragma unroll
    for (int tp = 0; tp < 8; ++tp) {          // level 1 (off 0)
        float4 p = pv[c0 * 8 + tp];
        #pragma unroll
        for (int r = 0; r < 4; ++r)
            acc[tp][r] = ggcd(acc[2*tp][r] * p.x, acc[2*tp+1][r] * p.y, p.z);
    }
    #pragma unroll
    for (int tp = 0; tp < 4; ++tp) {          // level 2 (off 128)
        float4 p = pv[128 + c0 * 4 + tp];
        #pragma unroll
        for (int r = 0; r < 4; ++r)
            acc[tp][r] = ggcd(acc[2*tp][r] * p.x, acc[2*tp+1][r] * p.y, p.z);
    }
    #pragma unroll
    for (int tp = 0; tp < 2; ++tp) {          // level 3 (off 192)
        float4 p = pv[192 + c0 * 2 + tp];
        #pragma unroll
        for (int r = 0; r < 4; ++r)
            acc[tp][r] = ggcd(acc[2*tp][r] * p.x, acc[2*tp+1][r] * p.y, p.z);
    }
    {                                          // level 4 (off 224)
        float4 p = pv[224 + c0];
        #pragma unroll
        for (int r = 0; r < 4; ++r)
            res[r] = ggcd(acc[0][r] * p.x, acc[1][r] * p.y, p.z);
    }
}

// ---- main (and only) kernel: one block per CU ----
__global__ __launch_bounds__(1024, 4)
void btln_main(const float* __restrict__ x, const float* __restrict__ Wl,
               const float* __restrict__ wts, const float* __restrict__ bia,
               const float* __restrict__ wout, const float* __restrict__ bout,
               float* __restrict__ out) {
    __shared__ short Wt[4][16384];           // 4 x 32 KB W K-tiles (all of W)
    __shared__ float4 pv[256];               // 4 KB packed (w0,w1,lam)

    const int tid  = threadIdx.x;
    const int lane = tid & 63;
    const int wv   = tid >> 6;               // wave 0..15
    const int c0   = lane & 15;
    const int q    = lane >> 4;

    // pv build (255 real entries + zero pad)
    if (tid < 255) {
        pv[tid] = make_float4(wts[2 * tid], wts[2 * tid + 1],
                              fast_sigmoid(bia[tid]), 0.f);
    } else if (tid == 255) {
        pv[255] = make_float4(0.f, 0.f, 0.f, 0.f);
    }

    // ---- prologue: stage ALL of W once (cold latency exposed once) ----
    // Thread owns 2 rows x 4 kt = 8 x 16B slots.
    // LDS byte kt*32768 + j*128 + scpos*16 holds bf16x8 of
    //   W[swap(j)][kt*64 + ((scpos^(j&7))<<3) .. +8)
    {
        const int scpos = tid & 7;
        const int sj    = (tid >> 3) & 63;
        const int half  = tid >> 9;                   // 0..1
        const int jA    = sj + 128 * half;
        const int jB    = jA + 64;
        const int colx  = (scpos ^ (sj & 7)) << 3;    // j&7 == sj&7 for both
        const int srcA  = ((jA & 15) << 4) | (jA >> 4);  // nibble-swap
        const int srcB  = ((jB & 15) << 4) | (jB >> 4);
        #pragma unroll
        for (int kt = 0; kt < 4; ++kt) {
            const float* pA = Wl + srcA * 256 + kt * 64 + colx;
            const float* pB = Wl + srcB * 256 + kt * 64 + colx;
            float4 a0 = *(const float4*)(pA);
            float4 a1 = *(const float4*)(pA + 4);
            float4 b0 = *(const float4*)(pB);
            float4 b1 = *(const float4*)(pB + 4);
            char* base = (char*)&Wt[kt][0] + scpos * 16;
            *(short8*)(base + jA * 128) = pack8(a0, a1);
            *(short8*)(base + jB * 128) = pack8(b0, b1);
        }
    }

    const int rowbase = blockIdx.x * 256 + wv * 16;
    const float* xr = x + (size_t)(rowbase + c0) * 256;

    // A-frags for tile 0 (lane(c0,q) <- row c0, k q*8.. / 32+q*8..)
    float4 r0 = *(const float4*)(xr + q * 8);
    float4 r1 = *(const float4*)(xr + q * 8 + 4);
    float4 r2 = *(const float4*)(xr + 32 + q * 8);
    float4 r3 = *(const float4*)(xr + 32 + q * 8 + 4);
    short8 afc0 = pack8(r0, r1);
    short8 afc1 = pack8(r2, r3);

    float4_t acc[16];
    #pragma unroll
    for (int t = 0; t < 16; ++t) acc[t] = (float4_t){0.f, 0.f, 0.f, 0.f};

    __syncthreads();                          // the ONLY barrier: W + pv resident

    const int vx = c0 & 7;

    // ---- K loop, fully unrolled, ZERO barriers ----
#define MFMA_T(t)                                                             \
    {                                                                         \
        const short* base = &cur[((t) * 16 + c0) * 64];                       \
        short8 bf0 = *(const short8*)&base[(q ^ vx) * 8];                     \
        short8 bf1 = *(const short8*)&base[((q + 4) ^ vx) * 8];               \
        acc[t] = __builtin_amdgcn_mfma_f32_16x16x32_bf16(                     \
            afc0, bf0, acc[t], 0, 0, 0);                                      \
        acc[t] = __builtin_amdgcn_mfma_f32_16x16x32_bf16(                     \
            afc1, bf1, acc[t], 0, 0, 0);                                      \
    }

#define KSTEP(kt, LAST)                                                       \
    {                                                                         \
        const short* cur = &Wt[kt][0];                                        \
        float4 n0, n1, n2, n3;                                                \
        if (!(LAST)) {                        /* issue next x frags early */  \
            const float* xn = xr + ((kt) + 1) * 64;                           \
            n0 = *(const float4*)(xn + q * 8);                                \
            n1 = *(const float4*)(xn + q * 8 + 4);                            \
            n2 = *(const float4*)(xn + 32 + q * 8);                           \
            n3 = *(const float4*)(xn + 32 + q * 8 + 4);                       \
        }                                                                     \
        _Pragma("unroll")                                                     \
        for (int t = 0; t < 16; ++t) MFMA_T(t)                                \
        if (!(LAST)) {                                                        \
            afc0 = pack8(n0, n1);                                             \
            afc1 = pack8(n2, n3);                                             \
        }                                                                     \
        __builtin_amdgcn_sched_barrier(0);    /* bound cross-kt hoisting */   \
    }

    KSTEP(0, 0)
    KSTEP(1, 0)
    KSTEP(2, 0)
    KSTEP(3, 1)
#undef KSTEP
#undef MFMA_T

    // ---- epilogue: leaf sigmoid + tree (acc[t][r]: row q*4+r, leaf c0*16+t) ----
    float res[4];
    tree_reduce(acc, c0, pv, res);

    const int offs[4] = {240, 248, 252, 254};
    #pragma unroll
    for (int k = 0; k < 4; ++k) {             // levels 5-8: butterfly across c0
        float4 p = pv[offs[k] + (c0 >> (k + 1))];
        bool isLeft = ((c0 >> k) & 1) == 0;
        #pragma unroll
        for (int r = 0; r < 4; ++r) {
            float other = __shfl_xor(res[r], 1 << k, 64);
            float lf = isLeft ? res[r] : other;
            float rt = isLeft ? other  : res[r];
            res[r] = ggcd(lf * p.x, rt * p.y, p.z);
        }
    }

    if (c0 == 0) {
        const float wo = wout[0];
        const float bo = bout[0];
        #pragma unroll
        for (int r = 0; r < 4; ++r)
            out[rowbase + q * 4 + r] = fast_sigmoid(fmaf(res[r], wo, bo));
    }
}

extern "C" void kernel_launch(void* const* d_in, const int* in_sizes, int n_in,
                              void* d_out, int out_size, void* d_ws, size_t ws_size,
                              hipStream_t stream) {
    const float* x   = (const float*)d_in[0];
    const float* Wl  = (const float*)d_in[1];
    const float* wts = (const float*)d_in[2];
    const float* bia = (const float*)d_in[3];
    const float* wo  = (const float*)d_in[4];
    const float* bo  = (const float*)d_in[5];
    float* out = (float*)d_out;

    const int rows = out_size;                // 65536
    dim3 grid(rows / 256), block(1024);       // 256 blocks = 1 per CU, 16 waves
    btln_main<<<grid, block, 0, stream>>>(x, Wl, wts, bia, wo, bo, out);
}

// Round 5
// 113.857 us; speedup vs baseline: 1.0635x; 1.0068x over previous
//
#include <hip/hip_runtime.h>
#include <stdint.h>

// BinaryTreeLogicNet: out = sigmoid(tree_gcd(sigmoid(x @ W^T - 2)) * w_out + b_out)
// M=65536 rows, L=256 leaves.
// R12: halve the LDS floor. Model (calibrated on R9 counters): steady-state
// floor = LDS B-frag streaming = #waves x 128 KB = 2 MB/CU ~ 10 us. Only
// lever is rows-per-wave (traffic ~ 1/r). Changes vs R11:
//   - 512 threads (8 waves), each wave computes 32 rows (two 16-row groups
//     A/B). Each ds_read_b128 B-frag feeds TWO MFMAs -> LDS traffic 1 MB/CU.
//   - __launch_bounds__(512,2): 256-VGPR cap (acc 128 + af 16 + prefetch 32
//     + addr ~ 205). 2 waves/SIMD; BW-bound regime so occupancy suffices.
//   - Still: all of W in LDS single-buffered (128 KB + 4 KB pv), staged once
//     in prologue (byte-identical swizzled layout: nibble-swap row permute +
//     cpos^(j&7) XOR), ONE barrier total, barrier-free K loop.
//   - MFMA read path + tree epilogue untouched per group (absmax 0.00390625).

#define EPS 1e-6f
#define LOG2E 1.44269504088896340736f

typedef __attribute__((ext_vector_type(8))) short short8;
typedef __attribute__((ext_vector_type(4))) short short4_t;
typedef __attribute__((ext_vector_type(4))) float float4_t;

__device__ __forceinline__ float fast_sigmoid(float z) {
    float e = __builtin_amdgcn_exp2f(-z * LOG2E);
    return __builtin_amdgcn_rcpf(1.0f + e);
}

__device__ __forceinline__ short f2bf(float f) {   // fp32 -> bf16 RNE
    uint32_t u = __builtin_bit_cast(uint32_t, f);
    u += 0x7FFFu + ((u >> 16) & 1u);
    return (short)(u >> 16);
}

__device__ __forceinline__ short8 pack8(float4 a, float4 b) {
    short8 s;
    s[0] = f2bf(a.x); s[1] = f2bf(a.y); s[2] = f2bf(a.z); s[3] = f2bf(a.w);
    s[4] = f2bf(b.x); s[5] = f2bf(b.y); s[6] = f2bf(b.z); s[7] = f2bf(b.w);
    return s;
}

__device__ __forceinline__ float ggcd(float l, float r, float lam) {
    float a = fabsf(l) + EPS;
    float b = fabsf(r) + EPS;
    float mn = fminf(a, b);
    float mx = fmaxf(a, b);
    return fmaf(lam, mn - mx, mx);   // lam*mn + (1-lam)*mx
}

// tree levels 1-4 on one 16-acc row-group; acc consumed in place
__device__ __forceinline__ void tree_reduce(float4_t acc[16], int c0,
                                            const float4* pv, float res[4]) {
    #pragma unroll
    for (int t = 0; t < 16; ++t) {
        #pragma unroll
        for (int r = 0; r < 4; ++r) acc[t][r] = fast_sigmoid(acc[t][r] - 2.0f);
    }
    #pragma unroll
    for (int tp = 0; tp < 8; ++tp) {          // level 1 (off 0)
        float4 p = pv[c0 * 8 + tp];
        #pragma unroll
        for (int r = 0; r < 4; ++r)
            acc[tp][r] = ggcd(acc[2*tp][r] * p.x, acc[2*tp+1][r] * p.y, p.z);
    }
    #pragma unroll
    for (int tp = 0; tp < 4; ++tp) {          // level 2 (off 128)
        float4 p = pv[128 + c0 * 4 + tp];
        #pragma unroll
        for (int r = 0; r < 4; ++r)
            acc[tp][r] = ggcd(acc[2*tp][r] * p.x, acc[2*tp+1][r] * p.y, p.z);
    }
    #pragma unroll
    for (int tp = 0; tp < 2; ++tp) {          // level 3 (off 192)
        float4 p = pv[192 + c0 * 2 + tp];
        #pragma unroll
        for (int r = 0; r < 4; ++r)
            acc[tp][r] = ggcd(acc[2*tp][r] * p.x, acc[2*tp+1][r] * p.y, p.z);
    }
    {                                          // level 4 (off 224)
        float4 p = pv[224 + c0];
        #pragma unroll
        for (int r = 0; r < 4; ++r)
            res[r] = ggcd(acc[0][r] * p.x, acc[1][r] * p.y, p.z);
    }
}

// butterfly levels 5-8 + final sigmoid + store for one 16-row group
__device__ __forceinline__ void tree_tail(float res[4], int c0, int q,
                                          const float4* pv, float wo, float bo,
                                          float* __restrict__ out, int rb) {
    const int offs[4] = {240, 248, 252, 254};
    #pragma unroll
    for (int k = 0; k < 4; ++k) {
        float4 p = pv[offs[k] + (c0 >> (k + 1))];
        bool isLeft = ((c0 >> k) & 1) == 0;
        #pragma unroll
        for (int r = 0; r < 4; ++r) {
            float other = __shfl_xor(res[r], 1 << k, 64);
            float lf = isLeft ? res[r] : other;
            float rt = isLeft ? other  : res[r];
            res[r] = ggcd(lf * p.x, rt * p.y, p.z);
        }
    }
    if (c0 == 0) {
        #pragma unroll
        for (int r = 0; r < 4; ++r)
            out[rb + q * 4 + r] = fast_sigmoid(fmaf(res[r], wo, bo));
    }
}

// ---- main (and only) kernel: one 512-thread block per CU ----
__global__ __launch_bounds__(512, 2)
void btln_main(const float* __restrict__ x, const float* __restrict__ Wl,
               const float* __restrict__ wts, const float* __restrict__ bia,
               const float* __restrict__ wout, const float* __restrict__ bout,
               float* __restrict__ out) {
    __shared__ short Wt[4][16384];           // 4 x 32 KB W K-tiles (all of W)
    __shared__ float4 pv[256];               // 4 KB packed (w0,w1,lam)

    const int tid  = threadIdx.x;
    const int lane = tid & 63;
    const int wv   = tid >> 6;               // wave 0..7
    const int c0   = lane & 15;
    const int q    = lane >> 4;

    // pv build (255 real entries + zero pad)
    if (tid < 255) {
        pv[tid] = make_float4(wts[2 * tid], wts[2 * tid + 1],
                              fast_sigmoid(bia[tid]), 0.f);
    } else if (tid == 255) {
        pv[255] = make_float4(0.f, 0.f, 0.f, 0.f);
    }

    // ---- prologue: stage ALL of W once (512 thr: 4 rows x 4 kt each) ----
    // LDS byte kt*32768 + j*128 + scpos*16 holds bf16x8 of
    //   W[swap(j)][kt*64 + ((scpos^(j&7))<<3) .. +8)
    {
        const int scpos = tid & 7;
        const int sj    = tid >> 3;                   // 0..63
        const int colx  = (scpos ^ (sj & 7)) << 3;    // j&7 == sj&7 for all 4 j
        #pragma unroll
        for (int half = 0; half < 4; ++half) {
            const int j   = sj + 64 * half;
            const int src = ((j & 15) << 4) | (j >> 4);  // nibble-swap
            #pragma unroll
            for (int kt = 0; kt < 4; ++kt) {
                const float* p = Wl + src * 256 + kt * 64 + colx;
                float4 a0 = *(const float4*)(p);
                float4 a1 = *(const float4*)(p + 4);
                *(short8*)((char*)&Wt[kt][0] + j * 128 + scpos * 16) = pack8(a0, a1);
            }
        }
    }

    const int rowbase = blockIdx.x * 256 + wv * 32;   // 8 waves x 32 rows
    const float* xrA = x + (size_t)(rowbase + c0) * 256;
    const float* xrB = x + (size_t)(rowbase + 16 + c0) * 256;

    // A-frags for tile 0, both row groups
    float4 r0 = *(const float4*)(xrA + q * 8);
    float4 r1 = *(const float4*)(xrA + q * 8 + 4);
    float4 r2 = *(const float4*)(xrA + 32 + q * 8);
    float4 r3 = *(const float4*)(xrA + 32 + q * 8 + 4);
    float4 s0 = *(const float4*)(xrB + q * 8);
    float4 s1 = *(const float4*)(xrB + q * 8 + 4);
    float4 s2 = *(const float4*)(xrB + 32 + q * 8);
    float4 s3 = *(const float4*)(xrB + 32 + q * 8 + 4);
    short8 afA0 = pack8(r0, r1);
    short8 afA1 = pack8(r2, r3);
    short8 afB0 = pack8(s0, s1);
    short8 afB1 = pack8(s2, s3);

    float4_t accA[16], accB[16];
    #pragma unroll
    for (int t = 0; t < 16; ++t) {
        accA[t] = (float4_t){0.f, 0.f, 0.f, 0.f};
        accB[t] = (float4_t){0.f, 0.f, 0.f, 0.f};
    }

    __syncthreads();                          // the ONLY barrier: W + pv resident

    const int vx = c0 & 7;

    // ---- K loop, fully unrolled, ZERO barriers; each B-frag feeds 2 MFMAs ----
#define MFMA_T(t)                                                             \
    {                                                                         \
        const short* base = &cur[((t) * 16 + c0) * 64];                       \
        short8 bf0 = *(const short8*)&base[(q ^ vx) * 8];                     \
        short8 bf1 = *(const short8*)&base[((q + 4) ^ vx) * 8];               \
        accA[t] = __builtin_amdgcn_mfma_f32_16x16x32_bf16(                    \
            afA0, bf0, accA[t], 0, 0, 0);                                     \
        accA[t] = __builtin_amdgcn_mfma_f32_16x16x32_bf16(                    \
            afA1, bf1, accA[t], 0, 0, 0);                                     \
        accB[t] = __builtin_amdgcn_mfma_f32_16x16x32_bf16(                    \
            afB0, bf0, accB[t], 0, 0, 0);                                     \
        accB[t] = __builtin_amdgcn_mfma_f32_16x16x32_bf16(                    \
            afB1, bf1, accB[t], 0, 0, 0);                                     \
    }

#define KSTEP(kt, LAST)                                                       \
    {                                                                         \
        const short* cur = &Wt[kt][0];                                        \
        float4 n0, n1, n2, n3, m0, m1, m2, m3;                                \
        if (!(LAST)) {                        /* issue next x frags early */  \
            const float* xnA = xrA + ((kt) + 1) * 64;                         \
            const float* xnB = xrB + ((kt) + 1) * 64;                         \
            n0 = *(const float4*)(xnA + q * 8);                               \
            n1 = *(const float4*)(xnA + q * 8 + 4);                           \
            n2 = *(const float4*)(xnA + 32 + q * 8);                          \
            n3 = *(const float4*)(xnA + 32 + q * 8 + 4);                      \
            m0 = *(const float4*)(xnB + q * 8);                               \
            m1 = *(const float4*)(xnB + q * 8 + 4);                           \
            m2 = *(const float4*)(xnB + 32 + q * 8);                          \
            m3 = *(const float4*)(xnB + 32 + q * 8 + 4);                      \
        }                                                                     \
        _Pragma("unroll")                                                     \
        for (int t = 0; t < 16; ++t) MFMA_T(t)                                \
        if (!(LAST)) {                                                        \
            afA0 = pack8(n0, n1);                                             \
            afA1 = pack8(n2, n3);                                             \
            afB0 = pack8(m0, m1);                                             \
            afB1 = pack8(m2, m3);                                             \
        }                                                                     \
        __builtin_amdgcn_sched_barrier(0);    /* bound cross-kt hoisting */   \
    }

    KSTEP(0, 0)
    KSTEP(1, 0)
    KSTEP(2, 0)
    KSTEP(3, 1)
#undef KSTEP
#undef MFMA_T

    // ---- epilogue: per-group leaf sigmoid + tree + butterfly + store ----
    const float wo = wout[0];
    const float bo = bout[0];
    {
        float res[4];
        tree_reduce(accA, c0, pv, res);
        tree_tail(res, c0, q, pv, wo, bo, out, rowbase);
    }
    {
        float res[4];
        tree_reduce(accB, c0, pv, res);
        tree_tail(res, c0, q, pv, wo, bo, out, rowbase + 16);
    }
}

extern "C" void kernel_launch(void* const* d_in, const int* in_sizes, int n_in,
                              void* d_out, int out_size, void* d_ws, size_t ws_size,
                              hipStream_t stream) {
    const float* x   = (const float*)d_in[0];
    const float* Wl  = (const float*)d_in[1];
    const float* wts = (const float*)d_in[2];
    const float* bia = (const float*)d_in[3];
    const float* wo  = (const float*)d_in[4];
    const float* bo  = (const float*)d_in[5];
    float* out = (float*)d_out;

    const int rows = out_size;                // 65536
    dim3 grid(rows / 256), block(512);        // 256 blocks = 1 per CU, 8 waves
    btln_main<<<grid, block, 0, stream>>>(x, Wl, wts, bia, wo, bo, out);
}

// Round 6
// 113.351 us; speedup vs baseline: 1.0683x; 1.0045x over previous
//
#include <hip/hip_runtime.h>
#include <stdint.h>

// BinaryTreeLogicNet: out = sigmoid(tree_gcd(sigmoid(x @ W^T - 2)) * w_out + b_out)
// M=65536 rows, L=256 leaves.
// R13: VALU-diet + conflict fix + 2-deep x pipeline. Evidence: R11->R12
// halved LDS traffic AND occupancy for -0.8us => neither binds. R9 counters:
// VALUBusy 21% x 52us ~ 11us/SIMD VALU = biggest real block; f2bf bit-twiddle
// (~32 VALU/pack8) is a large slice. pv[c0*8+tp] epilogue reads = stride
// 128B across c0 lanes = 16-way bank conflict (the real source of R9's 2.29M
// SQ_LDS_BANK_CONFLICT). Changes vs R12 (structure otherwise frozen):
//   - pack8 via v_cvt_pk_bf16_f32 (gfx950, RNE = bit-identical to old RNE
//     bit-twiddle): 32 VALU -> 4 instrs, in staging AND per-kt packs.
//   - pv remap idx->idx+(idx>>3) (288-slot padded table): 16-way -> 2-way.
//   - 2-deep x prefetch: tiles 0+1 issued in prologue; each kt packs a tile
//     issued a full kt earlier (~1100cyc) -> no vmcnt stalls. af dbuf'd.
//     Peak regs ~249 < 256 cap at (512,2).
//   - float4 out store.
//   - W LDS layout, MFMA read path, tree math untouched (absmax 0.00390625).

#define EPS 1e-6f
#define LOG2E 1.44269504088896340736f

typedef __attribute__((ext_vector_type(8))) short short8;
typedef __attribute__((ext_vector_type(4))) float float4_t;

__device__ __forceinline__ float fast_sigmoid(float z) {
    float e = __builtin_amdgcn_exp2f(-z * LOG2E);
    return __builtin_amdgcn_rcpf(1.0f + e);
}

// fp32x8 -> bf16x8 via v_cvt_pk_bf16_f32 (RNE, 2 floats/instr)
__device__ __forceinline__ short8 pack8(float4 a, float4 b) {
    uint32_t u0, u1, u2, u3;
    asm("v_cvt_pk_bf16_f32 %0, %1, %2" : "=v"(u0) : "v"(a.x), "v"(a.y));
    asm("v_cvt_pk_bf16_f32 %0, %1, %2" : "=v"(u1) : "v"(a.z), "v"(a.w));
    asm("v_cvt_pk_bf16_f32 %0, %1, %2" : "=v"(u2) : "v"(b.x), "v"(b.y));
    asm("v_cvt_pk_bf16_f32 %0, %1, %2" : "=v"(u3) : "v"(b.z), "v"(b.w));
    union { uint32_t u[4]; short8 s; } r;
    r.u[0] = u0; r.u[1] = u1; r.u[2] = u2; r.u[3] = u3;
    return r.s;
}

__device__ __forceinline__ float ggcd(float l, float r, float lam) {
    float a = fabsf(l) + EPS;
    float b = fabsf(r) + EPS;
    float mn = fminf(a, b);
    float mx = fmaxf(a, b);
    return fmaf(lam, mn - mx, mx);   // lam*mn + (1-lam)*mx
}

// padded pv index: +1 float4 gap every 8 entries -> c0-strided reads spread
// across banks (16-way -> 2-way)
__device__ __forceinline__ int pvIdx(int i) { return i + (i >> 3); }

// tree levels 1-4 on one 16-acc row-group; acc consumed in place
__device__ __forceinline__ void tree_reduce(float4_t acc[16], int c0,
                                            const float4* pv, float res[4]) {
    #pragma unroll
    for (int t = 0; t < 16; ++t) {
        #pragma unroll
        for (int r = 0; r < 4; ++r) acc[t][r] = fast_sigmoid(acc[t][r] - 2.0f);
    }
    #pragma unroll
    for (int tp = 0; tp < 8; ++tp) {          // level 1 (off 0)
        float4 p = pv[pvIdx(c0 * 8 + tp)];
        #pragma unroll
        for (int r = 0; r < 4; ++r)
            acc[tp][r] = ggcd(acc[2*tp][r] * p.x, acc[2*tp+1][r] * p.y, p.z);
    }
    #pragma unroll
    for (int tp = 0; tp < 4; ++tp) {          // level 2 (off 128)
        float4 p = pv[pvIdx(128 + c0 * 4 + tp)];
        #pragma unroll
        for (int r = 0; r < 4; ++r)
            acc[tp][r] = ggcd(acc[2*tp][r] * p.x, acc[2*tp+1][r] * p.y, p.z);
    }
    #pragma unroll
    for (int tp = 0; tp < 2; ++tp) {          // level 3 (off 192)
        float4 p = pv[pvIdx(192 + c0 * 2 + tp)];
        #pragma unroll
        for (int r = 0; r < 4; ++r)
            acc[tp][r] = ggcd(acc[2*tp][r] * p.x, acc[2*tp+1][r] * p.y, p.z);
    }
    {                                          // level 4 (off 224)
        float4 p = pv[pvIdx(224 + c0)];
        #pragma unroll
        for (int r = 0; r < 4; ++r)
            res[r] = ggcd(acc[0][r] * p.x, acc[1][r] * p.y, p.z);
    }
}

// butterfly levels 5-8 + final sigmoid + packed store for one 16-row group
__device__ __forceinline__ void tree_tail(float res[4], int c0, int q,
                                          const float4* pv, float wo, float bo,
                                          float* __restrict__ out, int rb) {
    const int offs[4] = {240, 248, 252, 254};
    #pragma unroll
    for (int k = 0; k < 4; ++k) {
        float4 p = pv[pvIdx(offs[k] + (c0 >> (k + 1)))];
        bool isLeft = ((c0 >> k) & 1) == 0;
        #pragma unroll
        for (int r = 0; r < 4; ++r) {
            float other = __shfl_xor(res[r], 1 << k, 64);
            float lf = isLeft ? res[r] : other;
            float rt = isLeft ? other  : res[r];
            res[r] = ggcd(lf * p.x, rt * p.y, p.z);
        }
    }
    if (c0 == 0) {
        float4 o;
        o.x = fast_sigmoid(fmaf(res[0], wo, bo));
        o.y = fast_sigmoid(fmaf(res[1], wo, bo));
        o.z = fast_sigmoid(fmaf(res[2], wo, bo));
        o.w = fast_sigmoid(fmaf(res[3], wo, bo));
        *(float4*)&out[rb + q * 4] = o;
    }
}

// ---- main (and only) kernel: one 512-thread block per CU ----
__global__ __launch_bounds__(512, 2)
void btln_main(const float* __restrict__ x, const float* __restrict__ Wl,
               const float* __restrict__ wts, const float* __restrict__ bia,
               const float* __restrict__ wout, const float* __restrict__ bout,
               float* __restrict__ out) {
    __shared__ short Wt[4][16384];           // 4 x 32 KB W K-tiles (all of W)
    __shared__ float4 pv[288];               // padded packed (w0,w1,lam)

    const int tid  = threadIdx.x;
    const int lane = tid & 63;
    const int wv   = tid >> 6;               // wave 0..7
    const int c0   = lane & 15;
    const int q    = lane >> 4;

    const int rowbase = blockIdx.x * 256 + wv * 32;   // 8 waves x 32 rows
    const float* xrA = x + (size_t)(rowbase + c0) * 256;
    const float* xrB = x + (size_t)(rowbase + 16 + c0) * 256;

#define LOADX(s0,s1,s2,s3,s4,s5,s6,s7, koff)                                  \
    s0 = *(const float4*)(xrA + (koff) + q * 8);                              \
    s1 = *(const float4*)(xrA + (koff) + q * 8 + 4);                          \
    s2 = *(const float4*)(xrA + (koff) + 32 + q * 8);                         \
    s3 = *(const float4*)(xrA + (koff) + 32 + q * 8 + 4);                     \
    s4 = *(const float4*)(xrB + (koff) + q * 8);                              \
    s5 = *(const float4*)(xrB + (koff) + q * 8 + 4);                          \
    s6 = *(const float4*)(xrB + (koff) + 32 + q * 8);                         \
    s7 = *(const float4*)(xrB + (koff) + 32 + q * 8 + 4);

#define PACKAF(A0,A1,B0,B1, s0,s1,s2,s3,s4,s5,s6,s7)                          \
    A0 = pack8(s0, s1); A1 = pack8(s2, s3);                                   \
    B0 = pack8(s4, s5); B1 = pack8(s6, s7);

    // ---- prologue: x tiles 0+1 in flight under pv build + W staging ----
    float4 P0,P1,P2,P3,P4,P5,P6,P7;
    float4 Q0,Q1,Q2,Q3,Q4,Q5,Q6,Q7;
    LOADX(P0,P1,P2,P3,P4,P5,P6,P7, 0)        // tile 0
    LOADX(Q0,Q1,Q2,Q3,Q4,Q5,Q6,Q7, 64)      // tile 1

    // pv build (255 real entries + zero pad), padded addressing
    if (tid < 255) {
        pv[pvIdx(tid)] = make_float4(wts[2 * tid], wts[2 * tid + 1],
                                     fast_sigmoid(bia[tid]), 0.f);
    } else if (tid == 255) {
        pv[pvIdx(255)] = make_float4(0.f, 0.f, 0.f, 0.f);
    }

    // stage ALL of W once (512 thr: 4 rows x 4 kt each)
    // LDS byte kt*32768 + j*128 + scpos*16 holds bf16x8 of
    //   W[swap(j)][kt*64 + ((scpos^(j&7))<<3) .. +8)
    {
        const int scpos = tid & 7;
        const int sj    = tid >> 3;                   // 0..63
        const int colx  = (scpos ^ (sj & 7)) << 3;    // j&7 == sj&7 for all 4 j
        #pragma unroll
        for (int half = 0; half < 4; ++half) {
            const int j   = sj + 64 * half;
            const int src = ((j & 15) << 4) | (j >> 4);  // nibble-swap
            #pragma unroll
            for (int kt = 0; kt < 4; ++kt) {
                const float* p = Wl + src * 256 + kt * 64 + colx;
                float4 a0 = *(const float4*)(p);
                float4 a1 = *(const float4*)(p + 4);
                *(short8*)((char*)&Wt[kt][0] + j * 128 + scpos * 16) = pack8(a0, a1);
            }
        }
    }

    // pack tile 0 (loads long arrived); tile-1 raw stays in flight/regs
    short8 aA0, aA1, aB0, aB1;                // current af
    short8 bA0, bA1, bB0, bB1;                // next af
    PACKAF(aA0,aA1,aB0,aB1, P0,P1,P2,P3,P4,P5,P6,P7)

    float4_t accA[16], accB[16];
    #pragma unroll
    for (int t = 0; t < 16; ++t) {
        accA[t] = (float4_t){0.f, 0.f, 0.f, 0.f};
        accB[t] = (float4_t){0.f, 0.f, 0.f, 0.f};
    }

    __syncthreads();                          // the ONLY barrier: W + pv resident

    const int vx = c0 & 7;

#define MFMA16(kt, A0,A1,B0,B1)                                               \
    {                                                                         \
        const short* cur = &Wt[kt][0];                                        \
        _Pragma("unroll")                                                     \
        for (int t = 0; t < 16; ++t) {                                        \
            const short* base = &cur[(t * 16 + c0) * 64];                     \
            short8 bf0 = *(const short8*)&base[(q ^ vx) * 8];                 \
            short8 bf1 = *(const short8*)&base[((q + 4) ^ vx) * 8];           \
            accA[t] = __builtin_amdgcn_mfma_f32_16x16x32_bf16(                \
                A0, bf0, accA[t], 0, 0, 0);                                   \
            accA[t] = __builtin_amdgcn_mfma_f32_16x16x32_bf16(                \
                A1, bf1, accA[t], 0, 0, 0);                                   \
            accB[t] = __builtin_amdgcn_mfma_f32_16x16x32_bf16(                \
                B0, bf0, accB[t], 0, 0, 0);                                   \
            accB[t] = __builtin_amdgcn_mfma_f32_16x16x32_bf16(                \
                B1, bf1, accB[t], 0, 0, 0);                                   \
        }                                                                     \
    }

    // kt0: pack tile1 (issued in prologue), issue tile2, MFMA tile0
    PACKAF(bA0,bA1,bB0,bB1, Q0,Q1,Q2,Q3,Q4,Q5,Q6,Q7)
    LOADX(P0,P1,P2,P3,P4,P5,P6,P7, 128)
    MFMA16(0, aA0,aA1,aB0,aB1)
    __builtin_amdgcn_sched_barrier(0);

    // kt1: pack tile2, issue tile3, MFMA tile1
    PACKAF(aA0,aA1,aB0,aB1, P0,P1,P2,P3,P4,P5,P6,P7)
    LOADX(Q0,Q1,Q2,Q3,Q4,Q5,Q6,Q7, 192)
    MFMA16(1, bA0,bA1,bB0,bB1)
    __builtin_amdgcn_sched_barrier(0);

    // kt2: pack tile3, MFMA tile2
    PACKAF(bA0,bA1,bB0,bB1, Q0,Q1,Q2,Q3,Q4,Q5,Q6,Q7)
    MFMA16(2, aA0,aA1,aB0,aB1)
    __builtin_amdgcn_sched_barrier(0);

    // kt3: MFMA tile3
    MFMA16(3, bA0,bA1,bB0,bB1)

#undef MFMA16
#undef LOADX
#undef PACKAF

    // ---- epilogue: per-group leaf sigmoid + tree + butterfly + store ----
    const float wo = wout[0];
    const float bo = bout[0];
    {
        float res[4];
        tree_reduce(accA, c0, pv, res);
        tree_tail(res, c0, q, pv, wo, bo, out, rowbase);
    }
    {
        float res[4];
        tree_reduce(accB, c0, pv, res);
        tree_tail(res, c0, q, pv, wo, bo, out, rowbase + 16);
    }
}

extern "C" void kernel_launch(void* const* d_in, const int* in_sizes, int n_in,
                              void* d_out, int out_size, void* d_ws, size_t ws_size,
                              hipStream_t stream) {
    const float* x   = (const float*)d_in[0];
    const float* Wl  = (const float*)d_in[1];
    const float* wts = (const float*)d_in[2];
    const float* bia = (const float*)d_in[3];
    const float* wo  = (const float*)d_in[4];
    const float* bo  = (const float*)d_in[5];
    float* out = (float*)d_out;

    const int rows = out_size;                // 65536
    dim3 grid(rows / 256), block(512);        // 256 blocks = 1 per CU, 8 waves
    btln_main<<<grid, block, 0, stream>>>(x, Wl, wts, bia, wo, bo, out);
}

// Round 7
// 113.020 us; speedup vs baseline: 1.0714x; 1.0029x over previous
//
#include <hip/hip_runtime.h>
#include <stdint.h>

// BinaryTreeLogicNet: out = sigmoid(tree_gcd(sigmoid(x @ W^T - 2)) * w_out + b_out)
// M=65536 rows, L=256 leaves.
// R14: scheduling polish on R13 (structure proven traffic-optimal: rows
// split across waves, W streamed from LDS 1 MB/CU; alternatives leaf-split /
// W-in-regs / 32x32 MFMA all analytically worse or equal). Changes vs R13:
//   - REMOVED the 3 cross-kt sched_barrier(0) fences: they pinned kt n+1
//     ds_reads below kt n MFMA tail (m141: order-pinning defeats the
//     scheduler). Compiler now free to software-pipeline across K-steps;
//     regalloc still targets 2 waves/SIMD so no spill expected.
//   - T5: s_setprio(1) around each MFMA cluster. Waves free-run at
//     different phases (zero steady-state barriers) = exactly the regime
//     where setprio paid (+4-7%, m191); null only in lockstep kernels.
//   - LOADX issued before PACKAF in source order per K-step.
//   - Numerics, LDS layout, MFMA read path, tree epilogue IDENTICAL
//     (verified absmax 0.00390625).

#define EPS 1e-6f
#define LOG2E 1.44269504088896340736f

typedef __attribute__((ext_vector_type(8))) short short8;
typedef __attribute__((ext_vector_type(4))) float float4_t;

__device__ __forceinline__ float fast_sigmoid(float z) {
    float e = __builtin_amdgcn_exp2f(-z * LOG2E);
    return __builtin_amdgcn_rcpf(1.0f + e);
}

// fp32x8 -> bf16x8 via v_cvt_pk_bf16_f32 (RNE, 2 floats/instr)
__device__ __forceinline__ short8 pack8(float4 a, float4 b) {
    uint32_t u0, u1, u2, u3;
    asm("v_cvt_pk_bf16_f32 %0, %1, %2" : "=v"(u0) : "v"(a.x), "v"(a.y));
    asm("v_cvt_pk_bf16_f32 %0, %1, %2" : "=v"(u1) : "v"(a.z), "v"(a.w));
    asm("v_cvt_pk_bf16_f32 %0, %1, %2" : "=v"(u2) : "v"(b.x), "v"(b.y));
    asm("v_cvt_pk_bf16_f32 %0, %1, %2" : "=v"(u3) : "v"(b.z), "v"(b.w));
    union { uint32_t u[4]; short8 s; } r;
    r.u[0] = u0; r.u[1] = u1; r.u[2] = u2; r.u[3] = u3;
    return r.s;
}

__device__ __forceinline__ float ggcd(float l, float r, float lam) {
    float a = fabsf(l) + EPS;
    float b = fabsf(r) + EPS;
    float mn = fminf(a, b);
    float mx = fmaxf(a, b);
    return fmaf(lam, mn - mx, mx);   // lam*mn + (1-lam)*mx
}

// padded pv index: +1 float4 gap every 8 entries -> c0-strided reads spread
// across banks (16-way -> 2-way)
__device__ __forceinline__ int pvIdx(int i) { return i + (i >> 3); }

// tree levels 1-4 on one 16-acc row-group; acc consumed in place
__device__ __forceinline__ void tree_reduce(float4_t acc[16], int c0,
                                            const float4* pv, float res[4]) {
    #pragma unroll
    for (int t = 0; t < 16; ++t) {
        #pragma unroll
        for (int r = 0; r < 4; ++r) acc[t][r] = fast_sigmoid(acc[t][r] - 2.0f);
    }
    #pragma unroll
    for (int tp = 0; tp < 8; ++tp) {          // level 1 (off 0)
        float4 p = pv[pvIdx(c0 * 8 + tp)];
        #pragma unroll
        for (int r = 0; r < 4; ++r)
            acc[tp][r] = ggcd(acc[2*tp][r] * p.x, acc[2*tp+1][r] * p.y, p.z);
    }
    #pragma unroll
    for (int tp = 0; tp < 4; ++tp) {          // level 2 (off 128)
        float4 p = pv[pvIdx(128 + c0 * 4 + tp)];
        #pragma unroll
        for (int r = 0; r < 4; ++r)
            acc[tp][r] = ggcd(acc[2*tp][r] * p.x, acc[2*tp+1][r] * p.y, p.z);
    }
    #pragma unroll
    for (int tp = 0; tp < 2; ++tp) {          // level 3 (off 192)
        float4 p = pv[pvIdx(192 + c0 * 2 + tp)];
        #pragma unroll
        for (int r = 0; r < 4; ++r)
            acc[tp][r] = ggcd(acc[2*tp][r] * p.x, acc[2*tp+1][r] * p.y, p.z);
    }
    {                                          // level 4 (off 224)
        float4 p = pv[pvIdx(224 + c0)];
        #pragma unroll
        for (int r = 0; r < 4; ++r)
            res[r] = ggcd(acc[0][r] * p.x, acc[1][r] * p.y, p.z);
    }
}

// butterfly levels 5-8 + final sigmoid + packed store for one 16-row group
__device__ __forceinline__ void tree_tail(float res[4], int c0, int q,
                                          const float4* pv, float wo, float bo,
                                          float* __restrict__ out, int rb) {
    const int offs[4] = {240, 248, 252, 254};
    #pragma unroll
    for (int k = 0; k < 4; ++k) {
        float4 p = pv[pvIdx(offs[k] + (c0 >> (k + 1)))];
        bool isLeft = ((c0 >> k) & 1) == 0;
        #pragma unroll
        for (int r = 0; r < 4; ++r) {
            float other = __shfl_xor(res[r], 1 << k, 64);
            float lf = isLeft ? res[r] : other;
            float rt = isLeft ? other  : res[r];
            res[r] = ggcd(lf * p.x, rt * p.y, p.z);
        }
    }
    if (c0 == 0) {
        float4 o;
        o.x = fast_sigmoid(fmaf(res[0], wo, bo));
        o.y = fast_sigmoid(fmaf(res[1], wo, bo));
        o.z = fast_sigmoid(fmaf(res[2], wo, bo));
        o.w = fast_sigmoid(fmaf(res[3], wo, bo));
        *(float4*)&out[rb + q * 4] = o;
    }
}

// ---- main (and only) kernel: one 512-thread block per CU ----
__global__ __launch_bounds__(512, 2)
void btln_main(const float* __restrict__ x, const float* __restrict__ Wl,
               const float* __restrict__ wts, const float* __restrict__ bia,
               const float* __restrict__ wout, const float* __restrict__ bout,
               float* __restrict__ out) {
    __shared__ short Wt[4][16384];           // 4 x 32 KB W K-tiles (all of W)
    __shared__ float4 pv[288];               // padded packed (w0,w1,lam)

    const int tid  = threadIdx.x;
    const int lane = tid & 63;
    const int wv   = tid >> 6;               // wave 0..7
    const int c0   = lane & 15;
    const int q    = lane >> 4;

    const int rowbase = blockIdx.x * 256 + wv * 32;   // 8 waves x 32 rows
    const float* xrA = x + (size_t)(rowbase + c0) * 256;
    const float* xrB = x + (size_t)(rowbase + 16 + c0) * 256;

#define LOADX(s0,s1,s2,s3,s4,s5,s6,s7, koff)                                  \
    s0 = *(const float4*)(xrA + (koff) + q * 8);                              \
    s1 = *(const float4*)(xrA + (koff) + q * 8 + 4);                          \
    s2 = *(const float4*)(xrA + (koff) + 32 + q * 8);                         \
    s3 = *(const float4*)(xrA + (koff) + 32 + q * 8 + 4);                     \
    s4 = *(const float4*)(xrB + (koff) + q * 8);                              \
    s5 = *(const float4*)(xrB + (koff) + q * 8 + 4);                          \
    s6 = *(const float4*)(xrB + (koff) + 32 + q * 8);                         \
    s7 = *(const float4*)(xrB + (koff) + 32 + q * 8 + 4);

#define PACKAF(A0,A1,B0,B1, s0,s1,s2,s3,s4,s5,s6,s7)                          \
    A0 = pack8(s0, s1); A1 = pack8(s2, s3);                                   \
    B0 = pack8(s4, s5); B1 = pack8(s6, s7);

    // ---- prologue: x tiles 0+1 in flight under pv build + W staging ----
    float4 P0,P1,P2,P3,P4,P5,P6,P7;
    float4 Q0,Q1,Q2,Q3,Q4,Q5,Q6,Q7;
    LOADX(P0,P1,P2,P3,P4,P5,P6,P7, 0)        // tile 0
    LOADX(Q0,Q1,Q2,Q3,Q4,Q5,Q6,Q7, 64)      // tile 1

    // pv build (255 real entries + zero pad), padded addressing
    if (tid < 255) {
        pv[pvIdx(tid)] = make_float4(wts[2 * tid], wts[2 * tid + 1],
                                     fast_sigmoid(bia[tid]), 0.f);
    } else if (tid == 255) {
        pv[pvIdx(255)] = make_float4(0.f, 0.f, 0.f, 0.f);
    }

    // stage ALL of W once (512 thr: 4 rows x 4 kt each)
    // LDS byte kt*32768 + j*128 + scpos*16 holds bf16x8 of
    //   W[swap(j)][kt*64 + ((scpos^(j&7))<<3) .. +8)
    {
        const int scpos = tid & 7;
        const int sj    = tid >> 3;                   // 0..63
        const int colx  = (scpos ^ (sj & 7)) << 3;    // j&7 == sj&7 for all 4 j
        #pragma unroll
        for (int half = 0; half < 4; ++half) {
            const int j   = sj + 64 * half;
            const int src = ((j & 15) << 4) | (j >> 4);  // nibble-swap
            #pragma unroll
            for (int kt = 0; kt < 4; ++kt) {
                const float* p = Wl + src * 256 + kt * 64 + colx;
                float4 a0 = *(const float4*)(p);
                float4 a1 = *(const float4*)(p + 4);
                *(short8*)((char*)&Wt[kt][0] + j * 128 + scpos * 16) = pack8(a0, a1);
            }
        }
    }

    // pack tile 0 (loads long arrived); tile-1 raw stays in flight/regs
    short8 aA0, aA1, aB0, aB1;                // current af
    short8 bA0, bA1, bB0, bB1;                // next af
    PACKAF(aA0,aA1,aB0,aB1, P0,P1,P2,P3,P4,P5,P6,P7)

    float4_t accA[16], accB[16];
    #pragma unroll
    for (int t = 0; t < 16; ++t) {
        accA[t] = (float4_t){0.f, 0.f, 0.f, 0.f};
        accB[t] = (float4_t){0.f, 0.f, 0.f, 0.f};
    }

    __syncthreads();                          // the ONLY barrier: W + pv resident

    const int vx = c0 & 7;

#define MFMA16(kt, A0,A1,B0,B1)                                               \
    {                                                                         \
        const short* cur = &Wt[kt][0];                                        \
        __builtin_amdgcn_s_setprio(1);                                        \
        _Pragma("unroll")                                                     \
        for (int t = 0; t < 16; ++t) {                                        \
            const short* base = &cur[(t * 16 + c0) * 64];                     \
            short8 bf0 = *(const short8*)&base[(q ^ vx) * 8];                 \
            short8 bf1 = *(const short8*)&base[((q + 4) ^ vx) * 8];           \
            accA[t] = __builtin_amdgcn_mfma_f32_16x16x32_bf16(                \
                A0, bf0, accA[t], 0, 0, 0);                                   \
            accA[t] = __builtin_amdgcn_mfma_f32_16x16x32_bf16(                \
                A1, bf1, accA[t], 0, 0, 0);                                   \
            accB[t] = __builtin_amdgcn_mfma_f32_16x16x32_bf16(                \
                B0, bf0, accB[t], 0, 0, 0);                                   \
            accB[t] = __builtin_amdgcn_mfma_f32_16x16x32_bf16(                \
                B1, bf1, accB[t], 0, 0, 0);                                   \
        }                                                                     \
        __builtin_amdgcn_s_setprio(0);                                        \
    }

    // kt0: issue tile2, pack tile1 (issued in prologue), MFMA tile0
    LOADX(P0,P1,P2,P3,P4,P5,P6,P7, 128)
    PACKAF(bA0,bA1,bB0,bB1, Q0,Q1,Q2,Q3,Q4,Q5,Q6,Q7)
    MFMA16(0, aA0,aA1,aB0,aB1)

    // kt1: issue tile3, pack tile2, MFMA tile1
    LOADX(Q0,Q1,Q2,Q3,Q4,Q5,Q6,Q7, 192)
    PACKAF(aA0,aA1,aB0,aB1, P0,P1,P2,P3,P4,P5,P6,P7)
    MFMA16(1, bA0,bA1,bB0,bB1)

    // kt2: pack tile3, MFMA tile2
    PACKAF(bA0,bA1,bB0,bB1, Q0,Q1,Q2,Q3,Q4,Q5,Q6,Q7)
    MFMA16(2, aA0,aA1,aB0,aB1)

    // kt3: MFMA tile3
    MFMA16(3, bA0,bA1,bB0,bB1)

#undef MFMA16
#undef LOADX
#undef PACKAF

    // ---- epilogue: per-group leaf sigmoid + tree + butterfly + store ----
    const float wo = wout[0];
    const float bo = bout[0];
    {
        float res[4];
        tree_reduce(accA, c0, pv, res);
        tree_tail(res, c0, q, pv, wo, bo, out, rowbase);
    }
    {
        float res[4];
        tree_reduce(accB, c0, pv, res);
        tree_tail(res, c0, q, pv, wo, bo, out, rowbase + 16);
    }
}

extern "C" void kernel_launch(void* const* d_in, const int* in_sizes, int n_in,
                              void* d_out, int out_size, void* d_ws, size_t ws_size,
                              hipStream_t stream) {
    const float* x   = (const float*)d_in[0];
    const float* Wl  = (const float*)d_in[1];
    const float* wts = (const float*)d_in[2];
    const float* bia = (const float*)d_in[3];
    const float* wo  = (const float*)d_in[4];
    const float* bo  = (const float*)d_in[5];
    float* out = (float*)d_out;

    const int rows = out_size;                // 65536
    dim3 grid(rows / 256), block(512);        // 256 blocks = 1 per CU, 8 waves
    btln_main<<<grid, block, 0, stream>>>(x, Wl, wts, bia, wo, bo, out);
}